// Round 12
// baseline (533.665 us; speedup 1.0000x reference)
//
#include <hip/hip_runtime.h>

// BinaryLSTMCell v10 for MI355X (gfx950) — ABLATION ROUND.
// Real kernel = v9b verbatim (MODE 4, writes d_out). Plus four timing probes
// (MODE 0..3) writing to d_ws, peeling the step apart:
//   MODE 0: MFMA only (operands in regs)       -> matrix-pipe capacity
//   MODE 1: + per-step ds_read_b128 x12        -> LDS-read exposure
//   MODE 2: + per-step staging VALU + ds_write -> staging exposure
//   MODE 3: + per-step lgkm-only barrier       -> sync exposure
//   main(4) - MODE3                            -> global-load exposure
// Invariant being attacked: MfmaUtil*dur == 55us MFMA content in ALL designs.

#define NB 65536

typedef _Float16 f16x8 __attribute__((ext_vector_type(8)));
typedef __fp16 fp16x2 __attribute__((ext_vector_type(2)));
typedef float f32x16 __attribute__((ext_vector_type(16)));

__device__ __forceinline__ float htanh(float x) {
  return __builtin_amdgcn_fmed3f(x, -1.0f, 1.0f);
}

// ---------------------------------------------------------------------------
// prep_w: W step-image [nb 8][s 16][kh 2][gate 4][lane 64][16B]  (1 MB total)
// ---------------------------------------------------------------------------
__global__ __launch_bounds__(512)
void prep_w(const float* __restrict__ Kf, const float* __restrict__ RKf,
            char* __restrict__ wimg) {
  const int b = blockIdx.x;                 // 128 = nb*16 + s
  const int s = b & 15;
  const int side = s >> 3, ks = s & 7;
  const float* M = side ? RKf : Kf;
  const int t = threadIdx.x;                // 512
  const int kh = t >> 8, gate = (t >> 6) & 3, l = t & 63;
  const int nb = b >> 4;
  const int col = gate * 256 + nb * 32 + (l & 31);
  const int k0 = ks * 32 + kh * 16 + (l >> 5) * 8;
  unsigned short o[8];
#pragma unroll
  for (int e = 0; e < 8; ++e)
    o[e] = (M[(k0 + e) * 1024 + col] >= 0.f) ? 0x3C00u : 0xBC00u;
  uint4 ov;
  ov.x = (unsigned)o[0] | ((unsigned)o[1] << 16);
  ov.y = (unsigned)o[2] | ((unsigned)o[3] << 16);
  ov.z = (unsigned)o[4] | ((unsigned)o[5] << 16);
  ov.w = (unsigned)o[6] | ((unsigned)o[7] << 16);
  *(uint4*)(wimg + (size_t)b * 8192 + kh * 4096 + gate * 1024 + l * 16) = ov;
}

// ---------------------------------------------------------------------------
template <int MODE>
__global__ __launch_bounds__(512, 1)
void blstm_main(const float* __restrict__ xin, const float* __restrict__ hin,
                const float* __restrict__ cin, const char* __restrict__ wimg,
                float* __restrict__ out) {
  extern __shared__ char smem0[];

  const int bid = blockIdx.x;
  const int xcd = bid & 7, ii = bid >> 3;
  const int mb = xcd * 32 + (ii >> 3), nb = ii & 7;
  const int m0 = mb << 8;

  const int tid = threadIdx.x, lane = tid & 63, w = tid >> 6;
  const int mw = w >> 1, nw = w & 1;
  const int l31 = lane & 31, lh = lane >> 5;

  const int sRow = tid >> 1, sKh = tid & 1;
  const int sMf = sRow >> 5, sL31 = sRow & 31;
  const int sSlot = (sL31 & 24) | ((sL31 ^ sMf) & 7);
  const float* const xrow = xin + (size_t)(m0 + sRow) * 256 + sKh * 16;
  const float* const hrow = hin + (size_t)(m0 + sRow) * 256 + sKh * 16;
  char* const aWrBase = smem0 + sMf * 1024 + sSlot * 16;
  const char* const wstep = wimg + (size_t)(nb * 16) * 8192 + tid * 16;

  const int lh512 = lh * 512;
  const int slotA0 = (l31 & 24) | ((l31 ^ (mw * 2 + 0)) & 7);
  const int slotA1 = (l31 & 24) | ((l31 ^ (mw * 2 + 1)) & 7);
  const int aOff0 = (mw * 2 + 0) * 1024 + slotA0 * 16;
  const int aOff1 = (mw * 2 + 1) * 1024 + slotA1 * 16;
  const int bOff0 = (nw * 2 + 0) * 1024 + lane * 16;
  const int bOff1 = (nw * 2 + 1) * 1024 + lane * 16;

  f32x16 acc[2][2][2] = {};
  uint4 bvA, bvB;
  float4 paA0, paA1, paA2, paA3, paB0, paB1, paB2, paB3;
  f16x8 rA[8], rB[4];   // MODE 0 only

#define BLOAD(BV, SP) BV = *(const uint4*)(wstep + (size_t)(SP) * 8192)

#define ALOADX(P0, P1, P2, P3, SP) do {                                       \
    const float* p_ = (((SP) >= 8) ? hrow : xrow) + ((SP) & 7) * 32;          \
    P0 = *(const float4*)(p_);      P1 = *(const float4*)(p_ + 4);            \
    P2 = *(const float4*)(p_ + 8);  P3 = *(const float4*)(p_ + 12);           \
  } while (0)

#define BSTORE(BV, SN) \
    *(uint4*)(smem0 + 65536 + ((SN) & 1) * 8192 + tid * 16) = BV

#define ACVT(P0, P1, P2, P3, SN) do {                                         \
    float e_[16] = {(P0).x, (P0).y, (P0).z, (P0).w,                           \
                    (P1).x, (P1).y, (P1).z, (P1).w,                           \
                    (P2).x, (P2).y, (P2).z, (P2).w,                           \
                    (P3).x, (P3).y, (P3).z, (P3).w};                          \
    if ((SN) >= 8) {                                                          \
      _Pragma("unroll") for (int i_ = 0; i_ < 16; ++i_) e_[i_] = htanh(e_[i_]); \
    }                                                                         \
    unsigned hw_[8], lw_[8];                                                  \
    _Pragma("unroll")                                                         \
    for (int i_ = 0; i_ < 8; ++i_) {                                          \
      fp16x2 h_ = __builtin_amdgcn_cvt_pkrtz(e_[2*i_], e_[2*i_+1]);           \
      hw_[i_] = __builtin_bit_cast(unsigned, h_);                             \
      fp16x2 l_ = __builtin_amdgcn_cvt_pkrtz(e_[2*i_]   - (float)h_[0],       \
                                             e_[2*i_+1] - (float)h_[1]);      \
      lw_[i_] = __builtin_bit_cast(unsigned, l_);                             \
    }                                                                         \
    char* b_ = aWrBase + ((SN) & 1) * 32768;                                  \
    *(uint4*)(b_ + sKh * 8192)             = make_uint4(hw_[0], hw_[1], hw_[2], hw_[3]); \
    *(uint4*)(b_ + sKh * 8192 + 512)       = make_uint4(hw_[4], hw_[5], hw_[6], hw_[7]); \
    *(uint4*)(b_ + (2 + sKh) * 8192)       = make_uint4(lw_[0], lw_[1], lw_[2], lw_[3]); \
    *(uint4*)(b_ + (2 + sKh) * 8192 + 512) = make_uint4(lw_[4], lw_[5], lw_[6], lw_[7]); \
  } while (0)

#define MM(AF, BF, AC) AC = __builtin_amdgcn_mfma_f32_32x32x16_f16(AF, BF, AC, 0, 0, 0)

#define COMP(S) do {                                                          \
    const char* a_ = smem0 + ((S) & 1) * 32768 + lh512;                       \
    const char* b_ = smem0 + 65536 + ((S) & 1) * 8192;                        \
    f16x8 B00 = *(const f16x8*)(b_ + bOff0);                                  \
    f16x8 B01 = *(const f16x8*)(b_ + bOff1);                                  \
    f16x8 B10 = *(const f16x8*)(b_ + 4096 + bOff0);                           \
    f16x8 B11 = *(const f16x8*)(b_ + 4096 + bOff1);                           \
    f16x8 A00 = *(const f16x8*)(a_ + 0 * 8192 + aOff0);                       \
    f16x8 A01 = *(const f16x8*)(a_ + 0 * 8192 + aOff1);                       \
    f16x8 A20 = *(const f16x8*)(a_ + 2 * 8192 + aOff0);                       \
    f16x8 A21 = *(const f16x8*)(a_ + 2 * 8192 + aOff1);                       \
    f16x8 A10 = *(const f16x8*)(a_ + 1 * 8192 + aOff0);                       \
    f16x8 A11 = *(const f16x8*)(a_ + 1 * 8192 + aOff1);                       \
    f16x8 A30 = *(const f16x8*)(a_ + 3 * 8192 + aOff0);                       \
    f16x8 A31 = *(const f16x8*)(a_ + 3 * 8192 + aOff1);                       \
    f32x16* ac = &acc[(S) >> 3][0][0];                                        \
    __builtin_amdgcn_s_setprio(1);                                            \
    MM(A00, B00, ac[0]); MM(A00, B01, ac[1]);                                 \
    MM(A01, B00, ac[2]); MM(A01, B01, ac[3]);                                 \
    MM(A20, B00, ac[0]); MM(A20, B01, ac[1]);                                 \
    MM(A21, B00, ac[2]); MM(A21, B01, ac[3]);                                 \
    MM(A10, B10, ac[0]); MM(A10, B11, ac[1]);                                 \
    MM(A11, B10, ac[2]); MM(A11, B11, ac[3]);                                 \
    MM(A30, B10, ac[0]); MM(A30, B11, ac[1]);                                 \
    MM(A31, B10, ac[2]); MM(A31, B11, ac[3]);                                 \
    __builtin_amdgcn_s_setprio(0);                                            \
  } while (0)

#define COMP0(S) do {                                                         \
    f32x16* ac = &acc[(S) >> 3][0][0];                                        \
    __builtin_amdgcn_s_setprio(1);                                            \
    MM(rA[0], rB[0], ac[0]); MM(rA[0], rB[1], ac[1]);                         \
    MM(rA[1], rB[0], ac[2]); MM(rA[1], rB[1], ac[3]);                         \
    MM(rA[4], rB[0], ac[0]); MM(rA[4], rB[1], ac[1]);                         \
    MM(rA[5], rB[0], ac[2]); MM(rA[5], rB[1], ac[3]);                         \
    MM(rA[2], rB[2], ac[0]); MM(rA[2], rB[3], ac[1]);                         \
    MM(rA[3], rB[2], ac[2]); MM(rA[3], rB[3], ac[3]);                         \
    MM(rA[6], rB[2], ac[0]); MM(rA[6], rB[3], ac[1]);                         \
    MM(rA[7], rB[2], ac[2]); MM(rA[7], rB[3], ac[3]);                         \
    __builtin_amdgcn_s_setprio(0);                                            \
  } while (0)

#define STEP(S, BVC, C0, C1, C2, C3, BVN, N0, N1, N2, N3) do {                \
    if constexpr (MODE == 4) {                                                \
      if ((S) < 14) { BLOAD(BVN, (S) + 2); ALOADX(N0, N1, N2, N3, (S) + 2); } \
    }                                                                         \
    if constexpr (MODE >= 2) {                                                \
      if ((S) < 15) { BSTORE(BVC, (S) + 1); ACVT(C0, C1, C2, C3, (S) + 1); }  \
    }                                                                         \
    if constexpr (MODE == 0) COMP0(S); else COMP(S);                          \
    if constexpr (MODE >= 3) {                                                \
      if ((S) < 15)                                                           \
        asm volatile("s_waitcnt lgkmcnt(0)\n\ts_barrier" ::: "memory");       \
    }                                                                         \
  } while (0)

  // ---- prologue ----
  BLOAD(bvA, 0); ALOADX(paA0, paA1, paA2, paA3, 0);
  BLOAD(bvB, 1); ALOADX(paB0, paB1, paB2, paB3, 1);
  BSTORE(bvA, 0); ACVT(paA0, paA1, paA2, paA3, 0);
  if constexpr (MODE != 4) { BSTORE(bvB, 1); ACVT(paB0, paB1, paB2, paB3, 1); }
  __syncthreads();
  if constexpr (MODE == 0) {
    const char* a_ = smem0 + lh512;
    const char* b_ = smem0 + 65536;
    rB[0] = *(const f16x8*)(b_ + bOff0);
    rB[1] = *(const f16x8*)(b_ + bOff1);
    rB[2] = *(const f16x8*)(b_ + 4096 + bOff0);
    rB[3] = *(const f16x8*)(b_ + 4096 + bOff1);
#pragma unroll
    for (int k = 0; k < 4; ++k) {
      rA[2 * k]     = *(const f16x8*)(a_ + k * 8192 + aOff0);
      rA[2 * k + 1] = *(const f16x8*)(a_ + k * 8192 + aOff1);
    }
  }
  if constexpr (MODE == 4)
    asm volatile("s_waitcnt lgkmcnt(0)\n\ts_barrier" ::: "memory");

  STEP(0,  bvB, paB0, paB1, paB2, paB3, bvA, paA0, paA1, paA2, paA3);
  STEP(1,  bvA, paA0, paA1, paA2, paA3, bvB, paB0, paB1, paB2, paB3);
  STEP(2,  bvB, paB0, paB1, paB2, paB3, bvA, paA0, paA1, paA2, paA3);
  STEP(3,  bvA, paA0, paA1, paA2, paA3, bvB, paB0, paB1, paB2, paB3);
  STEP(4,  bvB, paB0, paB1, paB2, paB3, bvA, paA0, paA1, paA2, paA3);
  STEP(5,  bvA, paA0, paA1, paA2, paA3, bvB, paB0, paB1, paB2, paB3);
  STEP(6,  bvB, paB0, paB1, paB2, paB3, bvA, paA0, paA1, paA2, paA3);
  STEP(7,  bvA, paA0, paA1, paA2, paA3, bvB, paB0, paB1, paB2, paB3);
  STEP(8,  bvB, paB0, paB1, paB2, paB3, bvA, paA0, paA1, paA2, paA3);
  STEP(9,  bvA, paA0, paA1, paA2, paA3, bvB, paB0, paB1, paB2, paB3);
  STEP(10, bvB, paB0, paB1, paB2, paB3, bvA, paA0, paA1, paA2, paA3);
  STEP(11, bvA, paA0, paA1, paA2, paA3, bvB, paB0, paB1, paB2, paB3);
  STEP(12, bvB, paB0, paB1, paB2, paB3, bvA, paA0, paA1, paA2, paA3);
  STEP(13, bvA, paA0, paA1, paA2, paA3, bvB, paB0, paB1, paB2, paB3);
  STEP(14, bvB, paB0, paB1, paB2, paB3, bvA, paA0, paA1, paA2, paA3);
  STEP(15, bvA, paA0, paA1, paA2, paA3, bvB, paB0, paB1, paB2, paB3);

#undef STEP
#undef COMP0
#undef COMP
#undef MM
#undef ACVT
#undef BSTORE
#undef ALOADX
#undef BLOAD

  if constexpr (MODE == 4) {
    // ---- v9b epilogue (verbatim) ----
    float* const exf = (float*)(smem0 + 81920);
    const int rowl = tid >> 3, u4g = (tid & 7) * 4;
#pragma unroll 1
    for (int p = 0; p < 4; ++p) {
      if (mw == p) {
#pragma unroll
        for (int side = 0; side < 2; ++side)
#pragma unroll
          for (int mfl = 0; mfl < 2; ++mfl)
#pragma unroll
            for (int nfl = 0; nfl < 2; ++nfl) {
              const int sgW = side * 4 + nw * 2 + nfl;
              float* bp = exf + sgW * 2304 + (mfl * 32 + lh * 4) * 36 + l31;
#pragma unroll
              for (int q = 0; q < 4; ++q)
#pragma unroll
                for (int rl = 0; rl < 4; ++rl)
                  bp[(q * 8 + rl) * 36] = acc[side][mfl][nfl][q * 4 + rl];
            }
      }
      const size_t obase = (size_t)(m0 + p * 64 + rowl) * 256 + nb * 32 + u4g;
      float4 cv = *(const float4*)(cin + obase);
      __syncthreads();
      {
        const float* rp = exf + rowl * 36 + u4g;
        float4 v0 = *(const float4*)(rp + 0 * 2304);
        float4 v1 = *(const float4*)(rp + 1 * 2304);
        float4 v2 = *(const float4*)(rp + 2 * 2304);
        float4 v3 = *(const float4*)(rp + 3 * 2304);
        float4 v4 = *(const float4*)(rp + 4 * 2304);
        float4 v5 = *(const float4*)(rp + 5 * 2304);
        float4 v6 = *(const float4*)(rp + 6 * 2304);
        float4 v7 = *(const float4*)(rp + 7 * 2304);
        float4 ho, co;
#pragma unroll
        for (int j = 0; j < 4; ++j) {
          const float xi = htanh(((const float*)&v0)[j]);
          const float xf = htanh(((const float*)&v1)[j]);
          const float xc = htanh(((const float*)&v2)[j]);
          const float xo = htanh(((const float*)&v3)[j]);
          const float fg   = htanh(xi + ((const float*)&v5)[j]);
          const float ig   = htanh(xf + ((const float*)&v4)[j]);
          const float cand = htanh(xc + ((const float*)&v6)[j]);
          const float og   = htanh(xo + ((const float*)&v7)[j]);
          const float ct = htanh(((const float*)&cv)[j]);
          const float cn = fg * ct + ig * cand;
          const float hn = htanh(og * htanh(cn));
          ((float*)&ho)[j] = hn;
          ((float*)&co)[j] = cn;
        }
        *(float4*)(out + obase) = ho;
        *(float4*)(out + (size_t)NB * 256 + obase) = ho;
        *(float4*)(out + 2 * (size_t)NB * 256 + obase) = co;
      }
      __syncthreads();
    }
  } else {
    // probe epilogue: reduce acc, one float4 per thread into probe buffer
    float s0 = 0.f, s1 = 0.f, s2 = 0.f, s3 = 0.f;
#pragma unroll
    for (int a = 0; a < 8; ++a) {
      const f32x16& v = acc[a >> 2][(a >> 1) & 1][a & 1];
#pragma unroll
      for (int q = 0; q < 4; ++q) {
        s0 += v[q * 4 + 0]; s1 += v[q * 4 + 1];
        s2 += v[q * 4 + 2]; s3 += v[q * 4 + 3];
      }
    }
    *(float4*)(out + ((size_t)bid * 512 + tid) * 4) = make_float4(s0, s1, s2, s3);
  }
}

extern "C" void kernel_launch(void* const* d_in, const int* in_sizes, int n_in,
                              void* d_out, int out_size, void* d_ws, size_t ws_size,
                              hipStream_t stream) {
  const float* xin = (const float*)d_in[0];
  const float* hin = (const float*)d_in[1];
  const float* cin = (const float*)d_in[2];
  const float* kf  = (const float*)d_in[3];
  const float* rkf = (const float*)d_in[4];
  float* out = (float*)d_out;

  char* wimg = (char*)d_ws;                     // 1 MB step-image
  float* p0 = (float*)((char*)d_ws + (size_t)(2 << 20));
  float* p1 = (float*)((char*)d_ws + (size_t)(20 << 20));
  float* p2 = (float*)((char*)d_ws + (size_t)(38 << 20));
  float* p3 = (float*)((char*)d_ws + (size_t)(56 << 20));

  (void)hipFuncSetAttribute((const void*)blstm_main<4>,
                            hipFuncAttributeMaxDynamicSharedMemorySize, 155648);
  (void)hipFuncSetAttribute((const void*)blstm_main<0>,
                            hipFuncAttributeMaxDynamicSharedMemorySize, 155648);
  (void)hipFuncSetAttribute((const void*)blstm_main<1>,
                            hipFuncAttributeMaxDynamicSharedMemorySize, 155648);
  (void)hipFuncSetAttribute((const void*)blstm_main<2>,
                            hipFuncAttributeMaxDynamicSharedMemorySize, 155648);
  (void)hipFuncSetAttribute((const void*)blstm_main<3>,
                            hipFuncAttributeMaxDynamicSharedMemorySize, 155648);

  prep_w<<<128, 512, 0, stream>>>(kf, rkf, wimg);
  blstm_main<4><<<2048, 512, 155648, stream>>>(xin, hin, cin, wimg, out);
  blstm_main<0><<<2048, 512, 155648, stream>>>(xin, hin, cin, wimg, p0);
  blstm_main<1><<<2048, 512, 155648, stream>>>(xin, hin, cin, wimg, p1);
  blstm_main<2><<<2048, 512, 155648, stream>>>(xin, hin, cin, wimg, p2);
  blstm_main<3><<<2048, 512, 155648, stream>>>(xin, hin, cin, wimg, p3);
}